// Round 18
// baseline (397.746 us; speedup 1.0000x reference)
//
#include <hip/hip_runtime.h>
#include <hip/hip_bf16.h>
#include <math.h>

#define N_IN 85680
#define PRE_K 5000
#define POST_K 750
#define NW 79            // ceil(PRE_K/64) words
#define NPAD 5056        // NW*64
#define HSIZE 8192       // linear buckets over score-bit range (0.02, +inf)
#define CAND_MAX 8192
#define CONF_THR 0.02f
#define NMS_THR 0.4f
#define BITS_THR 0x3CA3D70Bu  // bits of smallest float > 0.02f

typedef unsigned int u32;
typedef unsigned long long u64;

// column-major triangle-packed mask: word k's segment starts at cbase(k), holds
// rows 64k..NPAD-1. cbase(k) = k*(5088 - 32k)  [u64 units]; cbase(79)=202240.
__device__ __forceinline__ int cbase(int k) { return k * (5088 - 32 * k); }

// opacity barrier: prevents FMA contraction so f32 math bit-matches numpy ref
__device__ __forceinline__ float opaquef(float x) { asm volatile("" : "+v"(x)); return x; }

// wave-uniform 64-bit broadcast via v_readlane (src lane must be uniform)
__device__ __forceinline__ u64 readlane64(u64 v, int l) {
    u32 lo = __builtin_amdgcn_readlane((u32)v, l);
    u32 hi = __builtin_amdgcn_readlane((u32)(v >> 32), l);
    return ((u64)hi << 32) | (u64)lo;
}

// monotone bucket of a score's float bits (score > CONF_THR guaranteed)
__device__ __forceinline__ u32 bucket_of(u32 bits) {
    u32 b = (bits - BITS_THR) >> 13;
    return b >= HSIZE ? (HSIZE - 1) : b;
}

// ---------------- histogram of valid score buckets (multi-block) ----------------
__global__ __launch_bounds__(256) void hist_kernel(const float2* __restrict__ conf2,
                                                   u32* __restrict__ hist) {
    __shared__ u32 h[HSIZE];
    for (int b = threadIdx.x; b < HSIZE; b += 256) h[b] = 0u;
    __syncthreads();
    int i = blockIdx.x * 256 + threadIdx.x;
    if (i < N_IN) {
        float s = conf2[i].y;
        if (s > CONF_THR) atomicAdd(&h[bucket_of(__float_as_uint(s))], 1u);
    }
    __syncthreads();
    for (int b = threadIdx.x; b < HSIZE; b += 256) {
        u32 v = h[b];
        if (v) atomicAdd(&hist[b], v);
    }
}

// ---------------- suffix-scan: bstart[b] = #keys in buckets > b; bsel ----------------
__global__ __launch_bounds__(1024) void scan_kernel(const u32* __restrict__ hist,
                                                    u32* __restrict__ bsel,
                                                    u32* __restrict__ bstart) {
    __shared__ u32 tot[1024];
    int c = threadIdx.x;
    u32 lh[8];
    u32 t = 0;
#pragma unroll
    for (int k = 0; k < 8; ++k) { lh[k] = hist[c * 8 + k]; t += lh[k]; }
    tot[c] = t;
    __syncthreads();
    for (int d = 1; d < 1024; d <<= 1) {
        u32 v = tot[c] + ((c + d < 1024) ? tot[c + d] : 0u);
        __syncthreads();
        tot[c] = v;
        __syncthreads();
    }
    u32 above = (c + 1 < 1024) ? tot[c + 1] : 0u;
    u32 s = above;
    for (int k = 7; k >= 0; --k) { bstart[c * 8 + k] = s; s += lh[k]; }
    if (above < PRE_K && above + t >= PRE_K) {
        u32 cum = above;
        for (int k = 7; k >= 0; --k) {
            cum += lh[k];
            if (cum >= PRE_K) { bsel[0] = (u32)(c * 8 + k); break; }
        }
    }
    if (c == 0 && tot[0] < PRE_K) bsel[0] = 0u;
}

// ---------------- scatter candidates bucket-grouped ----------------
__global__ __launch_bounds__(256) void compact_kernel(const float2* __restrict__ conf2,
                                                      const u32* __restrict__ bsel,
                                                      const u32* __restrict__ bstart,
                                                      u32* __restrict__ bfill,
                                                      u64* __restrict__ cand) {
    int i = blockIdx.x * 256 + threadIdx.x;
    if (i >= N_IN) return;
    float sc = conf2[i].y;
    if (!(sc > CONF_THR)) return;
    u32 bits = __float_as_uint(sc);
    u32 b = bucket_of(bits);
    if (b < bsel[0]) return;
    u32 pos = bstart[b] + atomicAdd(&bfill[b], 1u);
    if (pos < CAND_MAX) cand[pos] = ((u64)bits << 32) | (u64)(u32)(~(u32)i);
}

// ---------------- fused: exact rank within bucket + decode -> rows/boxes/validm ----------------
__global__ __launch_bounds__(256) void rankdec_kernel(const u64* __restrict__ cand,
                                                      const u32* __restrict__ bstart,
                                                      const u32* __restrict__ bfill,
                                                      const u32* __restrict__ bsel,
                                                      const float4* __restrict__ loc4,
                                                      const float4* __restrict__ pri4,
                                                      const float* __restrict__ lmk,
                                                      const int* __restrict__ imw,
                                                      const int* __restrict__ imh,
                                                      float4* __restrict__ rows4,
                                                      float4* __restrict__ boxes,
                                                      u64* __restrict__ validm) {
    u32 bs = bsel[0];
    u32 total = bstart[bs] + bfill[bs];
    if (total > CAND_MAX) total = CAND_MAX;
    float W = (float)(*imw), H = (float)(*imh);
    for (u32 s = blockIdx.x * blockDim.x + threadIdx.x; s < total;
         s += gridDim.x * blockDim.x) {
        u64 key = cand[s];
        u32 b = bucket_of((u32)(key >> 32));
        u32 st = bstart[b];
        u32 en = st + bfill[b];
        if (en > CAND_MAX) en = CAND_MAX;
        u32 r = st;
        for (u32 j = st; j < en; ++j) r += (cand[j] > key) ? 1u : 0u;
        if (r >= PRE_K) continue;
        u32 i = ~(u32)key;
        float score = __uint_as_float((u32)(key >> 32));
        float4 L = loc4[i];
        float4 P = pri4[i];
        float cx = P.x + opaquef((L.x * 0.1f) * P.z);
        float cy = P.y + opaquef((L.y * 0.1f) * P.w);
        float bw = P.z * (float)exp((double)(L.z * 0.2f));
        float bh = P.w * (float)exp((double)(L.w * 0.2f));
        float hw = opaquef(bw * 0.5f), hh = opaquef(bh * 0.5f);
        float x0 = (cx - hw) * W, y0 = (cy - hh) * H;
        float x1 = (cx + hw) * W, y1 = (cy + hh) * H;
        boxes[r] = make_float4(x0, y0, x1, y1);
        float lm[10];
#pragma unroll
        for (int p = 0; p < 5; ++p) {
            float2 q = ((const float2*)lmk)[(size_t)i * 5 + p];
            lm[2 * p]     = (P.x + opaquef((q.x * 0.1f) * P.z)) * W;
            lm[2 * p + 1] = (P.y + opaquef((q.y * 0.1f) * P.w)) * H;
        }
        float4* row = rows4 + (size_t)r * 4;
        row[0] = make_float4(x0, y0, x1, y1);
        row[1] = make_float4(score, lm[0], lm[1], lm[2]);
        row[2] = make_float4(lm[3], lm[4], lm[5], lm[6]);
        row[3] = make_float4(lm[7], lm[8], lm[9], 0.f);
        atomicOr(&validm[r >> 6], 1ull << (r & 63));
    }
}

// ---------------- symmetric IoU bitmask, column-major triangle-packed ----------------
__global__ __launch_bounds__(64) void mask_kernel(const float4* __restrict__ boxes,
                                                  u64* __restrict__ cmask) {
    int rem = blockIdx.x, rc = 0;
    while (rem >= rc + 1) { rem -= rc + 1; ++rc; }
    int cc = rem;
    __shared__ float4 cb[64];
    int t = threadIdx.x;
    cb[t] = boxes[cc * 64 + t];
    int i = rc * 64 + t;
    float4 bi = boxes[i];
    __syncthreads();
    float areai = (bi.z - bi.x) * (bi.w - bi.y);
    u64 word = 0ull;
#pragma unroll 4
    for (int k = 0; k < 64; ++k) {
        float4 bj = cb[k];
        float areaj = (bj.z - bj.x) * (bj.w - bj.y);
        float ltx = fmaxf(bi.x, bj.x), lty = fmaxf(bi.y, bj.y);
        float rbx = fminf(bi.z, bj.z), rby = fminf(bi.w, bj.w);
        float wx = fmaxf(rbx - ltx, 0.f), wy = fmaxf(rby - lty, 0.f);
        float inter = opaquef(wx * wy);
        float uni = fmaxf(areai + areaj - inter, 1e-12f);
        float iou = inter / uni;
        if (iou > NMS_THR) word |= (1ull << k);
    }
    if (i < PRE_K) cmask[(size_t)(cbase(cc) + (i - 64 * cc))] = word;
}

// guarded coalesced column load for the fold pipeline
#define LDCOL(j, base, cnt) \
    (((j) < (cnt)) ? cmask[(size_t)(cbase((base) + (j)) + r - 64 * ((base) + (j)))] : 0ull)

// tight busy-poll on relaxed atomic; sentinel (> NW) -> dead (VAR==0 only)
#define WAITCNT(need)                                                                  \
    for (;;) {                                                                         \
        u32 d_ = __hip_atomic_load(&doneCnt, __ATOMIC_RELAXED,                         \
                                   __HIP_MEMORY_SCOPE_WORKGROUP);                      \
        if (d_ > (u32)NW) { dead = true; break; }                                      \
        if (d_ >= (u32)(need)) break;                                                  \
    }                                                                                  \
    asm volatile("" ::: "memory");

// no-early-exit variant wait (variants always run all 79 words)
#define WAITCNT_NE(need)                                                               \
    for (;;) {                                                                         \
        u32 d_ = __hip_atomic_load(&doneCnt, __ATOMIC_RELAXED,                         \
                                   __HIP_MEMORY_SCOPE_WORKGROUP);                      \
        if (d_ >= (u32)(need)) break;                                                  \
    }                                                                                  \
    asm volatile("" ::: "memory");

// ---------------- GS NMS + fused scatter — ABLATION TEMPLATE ----------------
// VAR=0: real R17 kernel (early-exit, writes `out`).       [the record path]
// VAR=1: memory-only — all loads, OR-sunk, no handshake/chain/early-exit.
// VAR=2: no-chain    — keptw = cur, no early-exit.
// VAR=3: no-fold     — fold loads+waits removed, chain intact, no early-exit.
// Variants write to scratch; rocprof per-dispatch rows give the 4-way split.
template<int VAR>
__global__ __launch_bounds__(512) void reduce_ablate(const u64* __restrict__ cmask,
                                                     const u64* __restrict__ validm,
                                                     const float* __restrict__ rows,
                                                     float* __restrict__ out) {
    int tid = threadIdx.x;
    int g = tid >> 6, lane = tid & 63;
    __shared__ u64 keepAll[96];
    __shared__ u32 totKs[96];
    __shared__ u32 doneCnt;
    __shared__ u32 wpref[96];
    for (int k = tid; k < 96; k += 512) keepAll[k] = 0ull;
    if (tid == 0) doneCnt = 0u;
    __syncthreads();
    u64 acc = 0ull;  // VAR==1 sink

    for (int s = 0; s < 10; ++s) {
        int w = s * 8 + g;
        if (w >= NW) break;
        int r = 64 * w + lane;
        u64 dreg = cmask[(size_t)(cbase(w) + lane)];
        u64 dA = (w >= 1) ? cmask[(size_t)(cbase(w - 1) + r - 64 * (w - 1))] : 0ull;
        u64 dB = (w >= 2) ? cmask[(size_t)(cbase(w - 2) + r - 64 * (w - 2))] : 0ull;
        u64 valw = validm[w];
        int wcap = (w >= 2) ? (w - 2) : 0;
        u64 sup = 0ull;
        bool dead = false;

        if constexpr (VAR == 1) {
            // memory-only: identical load pattern, no waits/handshakes
            acc |= dreg | dA | dB | valw;
            int d0 = 0;
            int nb = wcap < 8 ? wcap : 8;
            u64 c0 = LDCOL(0, 0, nb), c1 = LDCOL(1, 0, nb), c2 = LDCOL(2, 0, nb), c3 = LDCOL(3, 0, nb);
            u64 c4 = LDCOL(4, 0, nb), c5 = LDCOL(5, 0, nb), c6 = LDCOL(6, 0, nb), c7 = LDCOL(7, 0, nb);
            while (d0 < wcap) {
                int d1 = d0 + nb;
                int nb2 = wcap - d1; if (nb2 > 8) nb2 = 8;
                u64 n0 = LDCOL(0, d1, nb2), n1 = LDCOL(1, d1, nb2), n2 = LDCOL(2, d1, nb2), n3 = LDCOL(3, d1, nb2);
                u64 n4 = LDCOL(4, d1, nb2), n5 = LDCOL(5, d1, nb2), n6 = LDCOL(6, d1, nb2), n7 = LDCOL(7, d1, nb2);
                acc |= ((c0 | c1) | (c2 | c3)) | ((c4 | c5) | (c6 | c7));
                c0 = n0; c1 = n1; c2 = n2; c3 = n3; c4 = n4; c5 = n5; c6 = n6; c7 = n7;
                d0 = d1; nb = nb2;
            }
            acc |= ((c0 | c1) | (c2 | c3)) | ((c4 | c5) | (c6 | c7));
            continue;
        } else {
            if constexpr (VAR != 3) {
                // pipelined fold over predecessor words [0, wcap)
                int d0 = 0;
                int nb = wcap < 8 ? wcap : 8;
                u64 c0 = LDCOL(0, 0, nb), c1 = LDCOL(1, 0, nb), c2 = LDCOL(2, 0, nb), c3 = LDCOL(3, 0, nb);
                u64 c4 = LDCOL(4, 0, nb), c5 = LDCOL(5, 0, nb), c6 = LDCOL(6, 0, nb), c7 = LDCOL(7, 0, nb);
                while (d0 < wcap) {
                    int d1 = d0 + nb;
                    int nb2 = wcap - d1; if (nb2 > 8) nb2 = 8;
                    u64 n0 = LDCOL(0, d1, nb2), n1 = LDCOL(1, d1, nb2), n2 = LDCOL(2, d1, nb2), n3 = LDCOL(3, d1, nb2);
                    u64 n4 = LDCOL(4, d1, nb2), n5 = LDCOL(5, d1, nb2), n6 = LDCOL(6, d1, nb2), n7 = LDCOL(7, d1, nb2);
                    if constexpr (VAR == 0) { WAITCNT(d0 + nb) } else { WAITCNT_NE(d0 + nb) }
                    if (dead) break;
                    if (0 < nb) sup |= keepAll[d0 + 0] & c0;
                    if (1 < nb) sup |= keepAll[d0 + 1] & c1;
                    if (2 < nb) sup |= keepAll[d0 + 2] & c2;
                    if (3 < nb) sup |= keepAll[d0 + 3] & c3;
                    if (4 < nb) sup |= keepAll[d0 + 4] & c4;
                    if (5 < nb) sup |= keepAll[d0 + 5] & c5;
                    if (6 < nb) sup |= keepAll[d0 + 6] & c6;
                    if (7 < nb) sup |= keepAll[d0 + 7] & c7;
                    c0 = n0; c1 = n1; c2 = n2; c3 = n3; c4 = n4; c5 = n5; c6 = n6; c7 = n7;
                    d0 = d1; nb = nb2;
                }
            }
            // final handshake: word w-1 final
            if (!dead && w > 0) {
                if constexpr (VAR == 0) { WAITCNT(w) } else { WAITCNT_NE(w) }
            }
            u64 keptw = 0ull;
            u32 tp = 0u;
            if (!dead) {
                tp = (w > 0) ? totKs[w - 1] : 0u;
                if (VAR != 0 || tp < POST_K) {
                    if (w >= 2) sup |= keepAll[w - 2] & dB;
                    if (w >= 1) sup |= keepAll[w - 1] & dA;
                    u64 cur = valw & ~__ballot(sup != 0ull);
                    if constexpr (VAR == 2) {
                        keptw = cur;                 // chain skipped
                    } else {
                        while (cur) {                // wave-uniform chain
                            int b = __ffsll((long long)cur) - 1;
                            keptw |= (1ull << b);
                            u64 roww = readlane64(dreg, b);
                            cur &= ~(roww | (1ull << b));
                        }
                    }
                }
                if (lane == 0) {
                    u32 tk = tp + (u32)__popcll(keptw);
                    keepAll[w] = keptw;
                    totKs[w] = tk;
                    asm volatile("s_waitcnt lgkmcnt(0)" ::: "memory");
                    u32 flagv = (VAR == 0 && tk >= POST_K) ? (u32)(NW + 9) : (u32)(w + 1);
                    __hip_atomic_store(&doneCnt, flagv,
                                       __ATOMIC_RELAXED, __HIP_MEMORY_SCOPE_WORKGROUP);
                }
            }
        }
    }
    if constexpr (VAR == 1) {
        ((u64*)out)[tid] = acc;   // sink: keep every load live
        return;
    }
    __syncthreads();

    // word-prefix ranks + scatter (variants: to scratch — keeps keepAll live)
    if (tid == 0) {
        u32 s = 0;
        for (int w = 0; w < NW; ++w) { wpref[w] = s; s += (u32)__popcll(keepAll[w]); }
        wpref[NW] = s;
    }
    __syncthreads();
    u32 totk = wpref[NW]; if (totk > POST_K) totk = POST_K;
    for (int r = tid; r < PRE_K; r += 512) {
        int w = r >> 6, b = r & 63;
        u64 kw = keepAll[w];
        if ((kw >> b) & 1ull) {
            u32 rank = wpref[w] + (u32)__popcll(kw & ((1ull << b) - 1ull));
            if (rank < POST_K) {
                const float* src = rows + (size_t)r * 16;
                float* dst = out + (size_t)rank * 15;
#pragma unroll
                for (int c2 = 0; c2 < 15; ++c2) dst[c2] = src[c2];
            }
        }
    }
    for (int r = (int)totk + tid; r < POST_K; r += 512) {
        float* dst = out + (size_t)r * 15;
#pragma unroll
        for (int c2 = 0; c2 < 15; ++c2) dst[c2] = 0.f;
    }
}

extern "C" void kernel_launch(void* const* d_in, const int* in_sizes, int n_in,
                              void* d_out, int out_size, void* d_ws, size_t ws_size,
                              hipStream_t stream) {
    const float* loc = (const float*)d_in[0];
    const float2* conf2 = (const float2*)d_in[1];
    const float* lmk = (const float*)d_in[2];
    const float* pri = (const float*)d_in[3];
    const int* imw = (const int*)d_in[4];
    const int* imh = (const int*)d_in[5];
    float* out = (float*)d_out;
    char* base = (char*)d_ws;

    // workspace layout (bytes); total 2,229,824 (< 3,808,896 proven in R3-R17)
    u32* hist   = (u32*)(base + 0);         //  32768  [zeroed by memset]
    u32* bfill  = (u32*)(base + 32768);     //  32768  [zeroed]
    u32* bsel   = (u32*)(base + 65536);     //  64     [zeroed]
    u64* validm = (u64*)(base + 65600);     //  1024   [zeroed]  -> zero [0,66624)
    u32* bstart = (u32*)(base + 67648);     //  32768
    u64* cand   = (u64*)(base + 100416);    //  65536
    float* rows = (float*)(base + 165952);  //  320000 (5000 x 16)
    float4* boxes = (float4*)(base + 485952); // 80896 (NPAD x 16)
    u64* cmask  = (u64*)(base + 566848);    //  1617920 (202240 u64, triangle-packed)
    float* vout = (float*)(base + 2184768); //  45056  variant scratch "out"

    hipMemsetAsync(d_ws, 0, 66624, stream);

    hist_kernel<<<(N_IN + 255) / 256, 256, 0, stream>>>(conf2, hist);
    scan_kernel<<<1, 1024, 0, stream>>>(hist, bsel, bstart);
    compact_kernel<<<(N_IN + 255) / 256, 256, 0, stream>>>(conf2, bsel, bstart, bfill, cand);
    rankdec_kernel<<<24, 256, 0, stream>>>(cand, bstart, bfill, bsel, (const float4*)loc,
                                           (const float4*)pri, lmk, imw, imh,
                                           (float4*)rows, boxes, validm);
    mask_kernel<<<NW * (NW + 1) / 2, 64, 0, stream>>>(boxes, cmask);
    reduce_ablate<0><<<1, 512, 0, stream>>>(cmask, validm, rows, out);   // real
    reduce_ablate<1><<<1, 512, 0, stream>>>(cmask, validm, rows, vout);  // mem-only
    reduce_ablate<2><<<1, 512, 0, stream>>>(cmask, validm, rows, vout);  // no-chain
    reduce_ablate<3><<<1, 512, 0, stream>>>(cmask, validm, rows, vout);  // no-fold
}

// Round 19
// 110.867 us; speedup vs baseline: 3.5876x; 3.5876x over previous
//
#include <hip/hip_runtime.h>
#include <hip/hip_bf16.h>
#include <math.h>

#define N_IN 85680
#define PRE_K 5000
#define POST_K 750
#define NW 79            // ceil(PRE_K/64) words
#define NPAD 5056        // NW*64
#define HSIZE 8192       // linear buckets over score-bit range (0.02, +inf)
#define CAND_MAX 8192
#define CONF_THR 0.02f
#define NMS_THR 0.4f
#define BITS_THR 0x3CA3D70Bu  // bits of smallest float > 0.02f

typedef unsigned int u32;
typedef unsigned long long u64;

// column-major triangle-packed mask: word k's segment starts at cbase(k), holds
// rows 64k..NPAD-1. cbase(k) = k*(5088 - 32k)  [u64 units]; cbase(79)=202240.
__device__ __forceinline__ int cbase(int k) { return k * (5088 - 32 * k); }

// opacity barrier: prevents FMA contraction so f32 math bit-matches numpy ref
__device__ __forceinline__ float opaquef(float x) { asm volatile("" : "+v"(x)); return x; }

// monotone bucket of a score's float bits (score > CONF_THR guaranteed)
__device__ __forceinline__ u32 bucket_of(u32 bits) {
    u32 b = (bits - BITS_THR) >> 13;
    return b >= HSIZE ? (HSIZE - 1) : b;
}

// ---------------- histogram of valid score buckets (multi-block) ----------------
__global__ __launch_bounds__(256) void hist_kernel(const float2* __restrict__ conf2,
                                                   u32* __restrict__ hist) {
    __shared__ u32 h[HSIZE];
    for (int b = threadIdx.x; b < HSIZE; b += 256) h[b] = 0u;
    __syncthreads();
    int i = blockIdx.x * 256 + threadIdx.x;
    if (i < N_IN) {
        float s = conf2[i].y;
        if (s > CONF_THR) atomicAdd(&h[bucket_of(__float_as_uint(s))], 1u);
    }
    __syncthreads();
    for (int b = threadIdx.x; b < HSIZE; b += 256) {
        u32 v = h[b];
        if (v) atomicAdd(&hist[b], v);
    }
}

// ---------------- suffix-scan: bstart[b] = #keys in buckets > b; bsel ----------------
__global__ __launch_bounds__(1024) void scan_kernel(const u32* __restrict__ hist,
                                                    u32* __restrict__ bsel,
                                                    u32* __restrict__ bstart) {
    __shared__ u32 tot[1024];
    int c = threadIdx.x;
    u32 lh[8];
    u32 t = 0;
#pragma unroll
    for (int k = 0; k < 8; ++k) { lh[k] = hist[c * 8 + k]; t += lh[k]; }
    tot[c] = t;
    __syncthreads();
    for (int d = 1; d < 1024; d <<= 1) {
        u32 v = tot[c] + ((c + d < 1024) ? tot[c + d] : 0u);
        __syncthreads();
        tot[c] = v;
        __syncthreads();
    }
    u32 above = (c + 1 < 1024) ? tot[c + 1] : 0u;
    u32 s = above;
    for (int k = 7; k >= 0; --k) { bstart[c * 8 + k] = s; s += lh[k]; }
    if (above < PRE_K && above + t >= PRE_K) {
        u32 cum = above;
        for (int k = 7; k >= 0; --k) {
            cum += lh[k];
            if (cum >= PRE_K) { bsel[0] = (u32)(c * 8 + k); break; }
        }
    }
    if (c == 0 && tot[0] < PRE_K) bsel[0] = 0u;
}

// ---------------- scatter candidates bucket-grouped ----------------
__global__ __launch_bounds__(256) void compact_kernel(const float2* __restrict__ conf2,
                                                      const u32* __restrict__ bsel,
                                                      const u32* __restrict__ bstart,
                                                      u32* __restrict__ bfill,
                                                      u64* __restrict__ cand) {
    int i = blockIdx.x * 256 + threadIdx.x;
    if (i >= N_IN) return;
    float sc = conf2[i].y;
    if (!(sc > CONF_THR)) return;
    u32 bits = __float_as_uint(sc);
    u32 b = bucket_of(bits);
    if (b < bsel[0]) return;
    u32 pos = bstart[b] + atomicAdd(&bfill[b], 1u);
    if (pos < CAND_MAX) cand[pos] = ((u64)bits << 32) | (u64)(u32)(~(u32)i);
}

// ---------------- fused: exact rank within bucket + decode -> rows/boxes/validm ----------------
__global__ __launch_bounds__(256) void rankdec_kernel(const u64* __restrict__ cand,
                                                      const u32* __restrict__ bstart,
                                                      const u32* __restrict__ bfill,
                                                      const u32* __restrict__ bsel,
                                                      const float4* __restrict__ loc4,
                                                      const float4* __restrict__ pri4,
                                                      const float* __restrict__ lmk,
                                                      const int* __restrict__ imw,
                                                      const int* __restrict__ imh,
                                                      float4* __restrict__ rows4,
                                                      float4* __restrict__ boxes,
                                                      u64* __restrict__ validm) {
    u32 bs = bsel[0];
    u32 total = bstart[bs] + bfill[bs];
    if (total > CAND_MAX) total = CAND_MAX;
    float W = (float)(*imw), H = (float)(*imh);
    for (u32 s = blockIdx.x * blockDim.x + threadIdx.x; s < total;
         s += gridDim.x * blockDim.x) {
        u64 key = cand[s];
        u32 b = bucket_of((u32)(key >> 32));
        u32 st = bstart[b];
        u32 en = st + bfill[b];
        if (en > CAND_MAX) en = CAND_MAX;
        u32 r = st;
        for (u32 j = st; j < en; ++j) r += (cand[j] > key) ? 1u : 0u;
        if (r >= PRE_K) continue;
        u32 i = ~(u32)key;
        float score = __uint_as_float((u32)(key >> 32));
        float4 L = loc4[i];
        float4 P = pri4[i];
        float cx = P.x + opaquef((L.x * 0.1f) * P.z);
        float cy = P.y + opaquef((L.y * 0.1f) * P.w);
        float bw = P.z * (float)exp((double)(L.z * 0.2f));
        float bh = P.w * (float)exp((double)(L.w * 0.2f));
        float hw = opaquef(bw * 0.5f), hh = opaquef(bh * 0.5f);
        float x0 = (cx - hw) * W, y0 = (cy - hh) * H;
        float x1 = (cx + hw) * W, y1 = (cy + hh) * H;
        boxes[r] = make_float4(x0, y0, x1, y1);
        float lm[10];
#pragma unroll
        for (int p = 0; p < 5; ++p) {
            float2 q = ((const float2*)lmk)[(size_t)i * 5 + p];
            lm[2 * p]     = (P.x + opaquef((q.x * 0.1f) * P.z)) * W;
            lm[2 * p + 1] = (P.y + opaquef((q.y * 0.1f) * P.w)) * H;
        }
        float4* row = rows4 + (size_t)r * 4;
        row[0] = make_float4(x0, y0, x1, y1);
        row[1] = make_float4(score, lm[0], lm[1], lm[2]);
        row[2] = make_float4(lm[3], lm[4], lm[5], lm[6]);
        row[3] = make_float4(lm[7], lm[8], lm[9], 0.f);
        atomicOr(&validm[r >> 6], 1ull << (r & 63));
    }
}

// ---------------- symmetric IoU bitmask, column-major triangle-packed ----------------
__global__ __launch_bounds__(64) void mask_kernel(const float4* __restrict__ boxes,
                                                  u64* __restrict__ cmask) {
    int rem = blockIdx.x, rc = 0;
    while (rem >= rc + 1) { rem -= rc + 1; ++rc; }
    int cc = rem;
    __shared__ float4 cb[64];
    int t = threadIdx.x;
    cb[t] = boxes[cc * 64 + t];
    int i = rc * 64 + t;
    float4 bi = boxes[i];
    __syncthreads();
    float areai = (bi.z - bi.x) * (bi.w - bi.y);
    u64 word = 0ull;
#pragma unroll 4
    for (int k = 0; k < 64; ++k) {
        float4 bj = cb[k];
        float areaj = (bj.z - bj.x) * (bj.w - bj.y);
        float ltx = fmaxf(bi.x, bj.x), lty = fmaxf(bi.y, bj.y);
        float rbx = fminf(bi.z, bj.z), rby = fminf(bi.w, bj.w);
        float wx = fmaxf(rbx - ltx, 0.f), wy = fmaxf(rby - lty, 0.f);
        float inter = opaquef(wx * wy);
        float uni = fmaxf(areai + areaj - inter, 1e-12f);
        float iou = inter / uni;
        if (iou > NMS_THR) word |= (1ull << k);
    }
    if (i < PRE_K) cmask[(size_t)(cbase(cc) + (i - 64 * cc))] = word;
}

// guarded coalesced column load for the fold pipeline
#define LDCOL(j, base, cnt) \
    (((j) < (cnt)) ? cmask[(size_t)(cbase((base) + (j)) + r - 64 * ((base) + (j)))] : 0ull)

// tight busy-poll on relaxed atomic; sentinel (> NW) -> dead
#define WAITCNT(need)                                                                  \
    for (;;) {                                                                         \
        u32 d_ = __hip_atomic_load(&doneCnt, __ATOMIC_RELAXED,                         \
                                   __HIP_MEMORY_SCOPE_WORKGROUP);                      \
        if (d_ > (u32)NW) { dead = true; break; }                                      \
        if (d_ >= (u32)(need)) break;                                                  \
    }                                                                                  \
    asm volatile("" ::: "memory");

// ---------------- exact one-pass Gauss-Seidel NMS + fused scatter (1 block, 8 waves) ----
// v7: SUPPRESSED-ITERATION within-word solve. R18's ablation showed keeps are
// DENSE (~55/64 per word, early-exit at word ~14): the old chain paid one
// dependent ffs+readlane step per KEPT box (~55/word). New solve iterates one
// step per REMOVED box (~9/word): with S_b = row_b & below_b per-lane (dlow),
// the lowest contested box (S_b & keep != 0) is provably final-suppressed
// (its suppressors are below it, uncontested => final-kept), so remove it and
// re-ballot. Contestedness only shrinks as keep shrinks => exact greedy.
__global__ __launch_bounds__(512) void reduce_scatter_kernel(const u64* __restrict__ cmask,
                                                             const u64* __restrict__ validm,
                                                             const float* __restrict__ rows,
                                                             float* __restrict__ out) {
    int tid = threadIdx.x;
    int g = tid >> 6, lane = tid & 63;
    __shared__ u64 keepAll[96];
    __shared__ u32 totKs[96];
    __shared__ u32 doneCnt;   // # finalized words; NW+9 = early-exit sentinel
    __shared__ u32 wpref[96];
    for (int k = tid; k < 96; k += 512) keepAll[k] = 0ull;
    if (tid == 0) doneCnt = 0u;
    __syncthreads();
    u64 lmask = (1ull << lane) - 1ull;   // bits strictly below my lane (lane 63 ok)

    for (int s = 0; s < 10; ++s) {
        int w = s * 8 + g;
        if (w >= NW) break;
        int r = 64 * w + lane;
        // dlow = my potential same-word suppressors (strictly below me)
        u64 dlow = cmask[(size_t)(cbase(w) + lane)] & lmask;
        u64 dA = (w >= 1) ? cmask[(size_t)(cbase(w - 1) + r - 64 * (w - 1))] : 0ull;
        u64 dB = (w >= 2) ? cmask[(size_t)(cbase(w - 2) + r - 64 * (w - 2))] : 0ull;
        u64 valw = validm[w];                          // static: preload before waits
        int wcap = (w >= 2) ? (w - 2) : 0;
        u64 sup = 0ull;
        bool dead = false;

        // pipelined fold over predecessor words [0, wcap): 8-wide double-buffered,
        // individually named registers (no arrays -> no scratch spill)
        int d0 = 0;
        int nb = wcap < 8 ? wcap : 8;
        u64 c0 = LDCOL(0, 0, nb), c1 = LDCOL(1, 0, nb), c2 = LDCOL(2, 0, nb), c3 = LDCOL(3, 0, nb);
        u64 c4 = LDCOL(4, 0, nb), c5 = LDCOL(5, 0, nb), c6 = LDCOL(6, 0, nb), c7 = LDCOL(7, 0, nb);
        while (d0 < wcap) {
            int d1 = d0 + nb;
            int nb2 = wcap - d1; if (nb2 > 8) nb2 = 8;
            u64 n0 = LDCOL(0, d1, nb2), n1 = LDCOL(1, d1, nb2), n2 = LDCOL(2, d1, nb2), n3 = LDCOL(3, d1, nb2);
            u64 n4 = LDCOL(4, d1, nb2), n5 = LDCOL(5, d1, nb2), n6 = LDCOL(6, d1, nb2), n7 = LDCOL(7, d1, nb2);
            WAITCNT(d0 + nb)   // words d0..d0+nb-1 final
            if (dead) break;
            if (0 < nb) sup |= keepAll[d0 + 0] & c0;
            if (1 < nb) sup |= keepAll[d0 + 1] & c1;
            if (2 < nb) sup |= keepAll[d0 + 2] & c2;
            if (3 < nb) sup |= keepAll[d0 + 3] & c3;
            if (4 < nb) sup |= keepAll[d0 + 4] & c4;
            if (5 < nb) sup |= keepAll[d0 + 5] & c5;
            if (6 < nb) sup |= keepAll[d0 + 6] & c6;
            if (7 < nb) sup |= keepAll[d0 + 7] & c7;
            c0 = n0; c1 = n1; c2 = n2; c3 = n3; c4 = n4; c5 = n5; c6 = n6; c7 = n7;
            d0 = d1; nb = nb2;
        }
        // final handshake: word w-1 final
        if (!dead && w > 0) { WAITCNT(w) }
        u64 keep = 0ull;
        u32 tp = 0u;
        if (!dead) {
            tp = (w > 0) ? totKs[w - 1] : 0u;
            if (tp < POST_K) {
                if (w >= 2) sup |= keepAll[w - 2] & dB;
                if (w >= 1) sup |= keepAll[w - 1] & dA;
                keep = valw & ~__ballot(sup != 0ull);   // candidates
                // suppressed-iteration solve: one step per REMOVED box
                for (;;) {
                    bool con = (dlow & keep) != 0ull;   // am I currently suppressed?
                    u64 cm = __ballot(con) & keep;      // contested & still-candidate
                    if (cm == 0ull) break;
                    keep &= ~(cm & (~cm + 1ull));       // remove lowest contested (exact)
                }
            }
            if (lane == 0) {
                u32 tk = tp + (u32)__popcll(keep);
                keepAll[w] = keep;             // plain LDS stores...
                totKs[w] = tk;
                // ...ordered before the flag by lgkmcnt(0) (LDS-only; no vmcnt)
                asm volatile("s_waitcnt lgkmcnt(0)" ::: "memory");
                __hip_atomic_store(&doneCnt,
                                   (tk >= POST_K) ? (u32)(NW + 9) : (u32)(w + 1),
                                   __ATOMIC_RELAXED, __HIP_MEMORY_SCOPE_WORKGROUP);
            }
        }
        // dead waves: keepAll[w] stays 0 (rank-safe); do NOT touch doneCnt
    }
    __syncthreads();

    // word-prefix ranks
    if (tid == 0) {
        u32 s = 0;
        for (int w = 0; w < NW; ++w) { wpref[w] = s; s += (u32)__popcll(keepAll[w]); }
        wpref[NW] = s;
    }
    __syncthreads();
    u32 totk = wpref[NW]; if (totk > POST_K) totk = POST_K;
    for (int r = tid; r < PRE_K; r += 512) {
        int w = r >> 6, b = r & 63;
        u64 kw = keepAll[w];
        if ((kw >> b) & 1ull) {
            u32 rank = wpref[w] + (u32)__popcll(kw & ((1ull << b) - 1ull));
            if (rank < POST_K) {
                const float* src = rows + (size_t)r * 16;
                float* dst = out + (size_t)rank * 15;
#pragma unroll
                for (int c2 = 0; c2 < 15; ++c2) dst[c2] = src[c2];
            }
        }
    }
    for (int r = (int)totk + tid; r < POST_K; r += 512) {
        float* dst = out + (size_t)r * 15;
#pragma unroll
        for (int c2 = 0; c2 < 15; ++c2) dst[c2] = 0.f;
    }
}

extern "C" void kernel_launch(void* const* d_in, const int* in_sizes, int n_in,
                              void* d_out, int out_size, void* d_ws, size_t ws_size,
                              hipStream_t stream) {
    const float* loc = (const float*)d_in[0];
    const float2* conf2 = (const float2*)d_in[1];
    const float* lmk = (const float*)d_in[2];
    const float* pri = (const float*)d_in[3];
    const int* imw = (const int*)d_in[4];
    const int* imh = (const int*)d_in[5];
    float* out = (float*)d_out;
    char* base = (char*)d_ws;

    // workspace layout (bytes); total 2,184,768 (< 3,808,896 proven in R3-R18)
    u32* hist   = (u32*)(base + 0);         //  32768  [zeroed by memset]
    u32* bfill  = (u32*)(base + 32768);     //  32768  [zeroed]
    u32* bsel   = (u32*)(base + 65536);     //  64     [zeroed]
    u64* validm = (u64*)(base + 65600);     //  1024   [zeroed]  -> zero [0,66624)
    u32* bstart = (u32*)(base + 67648);     //  32768
    u64* cand   = (u64*)(base + 100416);    //  65536
    float* rows = (float*)(base + 165952);  //  320000 (5000 x 16)
    float4* boxes = (float4*)(base + 485952); // 80896 (NPAD x 16)
    u64* cmask  = (u64*)(base + 566848);    //  1617920 (202240 u64, triangle-packed)

    hipMemsetAsync(d_ws, 0, 66624, stream);

    hist_kernel<<<(N_IN + 255) / 256, 256, 0, stream>>>(conf2, hist);
    scan_kernel<<<1, 1024, 0, stream>>>(hist, bsel, bstart);
    compact_kernel<<<(N_IN + 255) / 256, 256, 0, stream>>>(conf2, bsel, bstart, bfill, cand);
    rankdec_kernel<<<24, 256, 0, stream>>>(cand, bstart, bfill, bsel, (const float4*)loc,
                                           (const float4*)pri, lmk, imw, imh,
                                           (float4*)rows, boxes, validm);
    mask_kernel<<<NW * (NW + 1) / 2, 64, 0, stream>>>(boxes, cmask);
    reduce_scatter_kernel<<<1, 512, 0, stream>>>(cmask, validm, rows, out);
}

// Round 20
// 94.778 us; speedup vs baseline: 4.1966x; 1.1698x over previous
//
#include <hip/hip_runtime.h>
#include <hip/hip_bf16.h>
#include <math.h>

#define N_IN 85680
#define PRE_K 5000
#define POST_K 750
#define NW 79            // ceil(PRE_K/64) words
#define NPAD 5056        // NW*64
#define HSIZE 8192       // linear buckets over score-bit range (0.02, +inf)
#define CAND_MAX 8192
#define CONF_THR 0.02f
#define NMS_THR 0.4f
#define BITS_THR 0x3CA3D70Bu  // bits of smallest float > 0.02f
#define NGRP 20          // ceil(NW/4) word-groups for the GS chain

typedef unsigned int u32;
typedef unsigned long long u64;

// column-major triangle-packed mask: word k's segment starts at cbase(k), holds
// rows 64k..NPAD-1. cbase(k) = k*(5088 - 32k)  [u64 units]; cbase(79)=202240.
__device__ __forceinline__ int cbase(int k) { return k * (5088 - 32 * k); }

// opacity barrier: prevents FMA contraction so f32 math bit-matches numpy ref
__device__ __forceinline__ float opaquef(float x) { asm volatile("" : "+v"(x)); return x; }

// monotone bucket of a score's float bits (score > CONF_THR guaranteed)
__device__ __forceinline__ u32 bucket_of(u32 bits) {
    u32 b = (bits - BITS_THR) >> 13;
    return b >= HSIZE ? (HSIZE - 1) : b;
}

// ---------------- histogram of valid score buckets (multi-block) ----------------
__global__ __launch_bounds__(256) void hist_kernel(const float2* __restrict__ conf2,
                                                   u32* __restrict__ hist) {
    __shared__ u32 h[HSIZE];
    for (int b = threadIdx.x; b < HSIZE; b += 256) h[b] = 0u;
    __syncthreads();
    int i = blockIdx.x * 256 + threadIdx.x;
    if (i < N_IN) {
        float s = conf2[i].y;
        if (s > CONF_THR) atomicAdd(&h[bucket_of(__float_as_uint(s))], 1u);
    }
    __syncthreads();
    for (int b = threadIdx.x; b < HSIZE; b += 256) {
        u32 v = h[b];
        if (v) atomicAdd(&hist[b], v);
    }
}

// ---------------- suffix-scan: bstart[b] = #keys in buckets > b; bsel ----------------
__global__ __launch_bounds__(1024) void scan_kernel(const u32* __restrict__ hist,
                                                    u32* __restrict__ bsel,
                                                    u32* __restrict__ bstart) {
    __shared__ u32 tot[1024];
    int c = threadIdx.x;
    u32 lh[8];
    u32 t = 0;
#pragma unroll
    for (int k = 0; k < 8; ++k) { lh[k] = hist[c * 8 + k]; t += lh[k]; }
    tot[c] = t;
    __syncthreads();
    for (int d = 1; d < 1024; d <<= 1) {
        u32 v = tot[c] + ((c + d < 1024) ? tot[c + d] : 0u);
        __syncthreads();
        tot[c] = v;
        __syncthreads();
    }
    u32 above = (c + 1 < 1024) ? tot[c + 1] : 0u;
    u32 s = above;
    for (int k = 7; k >= 0; --k) { bstart[c * 8 + k] = s; s += lh[k]; }
    if (above < PRE_K && above + t >= PRE_K) {
        u32 cum = above;
        for (int k = 7; k >= 0; --k) {
            cum += lh[k];
            if (cum >= PRE_K) { bsel[0] = (u32)(c * 8 + k); break; }
        }
    }
    if (c == 0 && tot[0] < PRE_K) bsel[0] = 0u;
}

// ---------------- scatter candidates bucket-grouped ----------------
__global__ __launch_bounds__(256) void compact_kernel(const float2* __restrict__ conf2,
                                                      const u32* __restrict__ bsel,
                                                      const u32* __restrict__ bstart,
                                                      u32* __restrict__ bfill,
                                                      u64* __restrict__ cand) {
    int i = blockIdx.x * 256 + threadIdx.x;
    if (i >= N_IN) return;
    float sc = conf2[i].y;
    if (!(sc > CONF_THR)) return;
    u32 bits = __float_as_uint(sc);
    u32 b = bucket_of(bits);
    if (b < bsel[0]) return;
    u32 pos = bstart[b] + atomicAdd(&bfill[b], 1u);
    if (pos < CAND_MAX) cand[pos] = ((u64)bits << 32) | (u64)(u32)(~(u32)i);
}

// ---------------- fused: exact rank within bucket + decode -> rows/boxes/validm ----------------
__global__ __launch_bounds__(256) void rankdec_kernel(const u64* __restrict__ cand,
                                                      const u32* __restrict__ bstart,
                                                      const u32* __restrict__ bfill,
                                                      const u32* __restrict__ bsel,
                                                      const float4* __restrict__ loc4,
                                                      const float4* __restrict__ pri4,
                                                      const float* __restrict__ lmk,
                                                      const int* __restrict__ imw,
                                                      const int* __restrict__ imh,
                                                      float4* __restrict__ rows4,
                                                      float4* __restrict__ boxes,
                                                      u64* __restrict__ validm) {
    u32 bs = bsel[0];
    u32 total = bstart[bs] + bfill[bs];
    if (total > CAND_MAX) total = CAND_MAX;
    float W = (float)(*imw), H = (float)(*imh);
    for (u32 s = blockIdx.x * blockDim.x + threadIdx.x; s < total;
         s += gridDim.x * blockDim.x) {
        u64 key = cand[s];
        u32 b = bucket_of((u32)(key >> 32));
        u32 st = bstart[b];
        u32 en = st + bfill[b];
        if (en > CAND_MAX) en = CAND_MAX;
        u32 r = st;
        for (u32 j = st; j < en; ++j) r += (cand[j] > key) ? 1u : 0u;
        if (r >= PRE_K) continue;
        u32 i = ~(u32)key;
        float score = __uint_as_float((u32)(key >> 32));
        float4 L = loc4[i];
        float4 P = pri4[i];
        float cx = P.x + opaquef((L.x * 0.1f) * P.z);
        float cy = P.y + opaquef((L.y * 0.1f) * P.w);
        float bw = P.z * (float)exp((double)(L.z * 0.2f));
        float bh = P.w * (float)exp((double)(L.w * 0.2f));
        float hw = opaquef(bw * 0.5f), hh = opaquef(bh * 0.5f);
        float x0 = (cx - hw) * W, y0 = (cy - hh) * H;
        float x1 = (cx + hw) * W, y1 = (cy + hh) * H;
        boxes[r] = make_float4(x0, y0, x1, y1);
        float lm[10];
#pragma unroll
        for (int p = 0; p < 5; ++p) {
            float2 q = ((const float2*)lmk)[(size_t)i * 5 + p];
            lm[2 * p]     = (P.x + opaquef((q.x * 0.1f) * P.z)) * W;
            lm[2 * p + 1] = (P.y + opaquef((q.y * 0.1f) * P.w)) * H;
        }
        float4* row = rows4 + (size_t)r * 4;
        row[0] = make_float4(x0, y0, x1, y1);
        row[1] = make_float4(score, lm[0], lm[1], lm[2]);
        row[2] = make_float4(lm[3], lm[4], lm[5], lm[6]);
        row[3] = make_float4(lm[7], lm[8], lm[9], 0.f);
        atomicOr(&validm[r >> 6], 1ull << (r & 63));
    }
}

// ---------------- symmetric IoU bitmask, column-major triangle-packed ----------------
__global__ __launch_bounds__(64) void mask_kernel(const float4* __restrict__ boxes,
                                                  u64* __restrict__ cmask) {
    int rem = blockIdx.x, rc = 0;
    while (rem >= rc + 1) { rem -= rc + 1; ++rc; }
    int cc = rem;
    __shared__ float4 cb[64];
    int t = threadIdx.x;
    cb[t] = boxes[cc * 64 + t];
    int i = rc * 64 + t;
    float4 bi = boxes[i];
    __syncthreads();
    float areai = (bi.z - bi.x) * (bi.w - bi.y);
    u64 word = 0ull;
#pragma unroll 4
    for (int k = 0; k < 64; ++k) {
        float4 bj = cb[k];
        float areaj = (bj.z - bj.x) * (bj.w - bj.y);
        float ltx = fmaxf(bi.x, bj.x), lty = fmaxf(bi.y, bj.y);
        float rbx = fminf(bi.z, bj.z), rby = fminf(bi.w, bj.w);
        float wx = fmaxf(rbx - ltx, 0.f), wy = fmaxf(rby - lty, 0.f);
        float inter = opaquef(wx * wy);
        float uni = fmaxf(areai + areaj - inter, 1e-12f);
        float iou = inter / uni;
        if (iou > NMS_THR) word |= (1ull << k);
    }
    if (i < PRE_K) cmask[(size_t)(cbase(cc) + (i - 64 * cc))] = word;
}

// coalesced column load: word k, global row q
#define FC(k, q) cmask[(size_t)(cbase(k) + (q) - 64 * (k))]

// tight busy-poll on relaxed group counter; sentinel (> NGRP) -> dead
#define WAITG(need)                                                                   \
    for (;;) {                                                                        \
        u32 d_ = __hip_atomic_load(&doneCnt, __ATOMIC_RELAXED,                        \
                                   __HIP_MEMORY_SCOPE_WORKGROUP);                     \
        if (d_ > (u32)NGRP) { dead = true; break; }                                   \
        if (d_ >= (u32)(need)) break;                                                 \
    }                                                                                 \
    asm volatile("" ::: "memory");

// exact greedy within-word solve, LEVEL-WISE: each iteration finalizes one level
// of the suppression DAG. U = candidates with no candidate suppressor (final
// kept); rem = candidates suppressed by some U member (final removed). The
// lowest contested candidate always lands in rem => guaranteed progress; exact.
__device__ __forceinline__ u64 nms_solve(u64 valw, u64 sup, u64 dlow) {
    u64 keep = valw & ~__ballot(sup != 0ull);
    for (;;) {
        u64 conm = __ballot((dlow & keep) != 0ull);
        u64 cm = conm & keep;
        if (cm == 0ull) break;
        u64 U = keep & ~conm;
        u64 rem = __ballot((dlow & U) != 0ull) & keep;
        keep &= ~rem;
    }
    return keep;
}

// ---------------- exact one-pass GS NMS + fused scatter (1 block, 8 waves) ----------
// v8: GROUP-OF-4 handshake + level-wise solve. Wave g owns group G=s*8+g (4
// consecutive words); in-group cross-word suppression via a 10-reg 4x4 tile
// (named regs — no arrays, no spill); fold covers ALL predecessor words with
// 2-word x 4-row double-buffered batches whose final wait doubles as the group
// handshake (release events: 79 -> 20, early-exit ~5). Level-wise solve is
// ~chain-depth (~4) iterations/word instead of ~#removed (~27).
__global__ __launch_bounds__(512) void reduce_scatter_kernel(const u64* __restrict__ cmask,
                                                             const u64* __restrict__ validm,
                                                             const float* __restrict__ rows,
                                                             float* __restrict__ out) {
    int tid = threadIdx.x;
    int g = tid >> 6, lane = tid & 63;
    __shared__ u64 keepAll[96];
    __shared__ u32 totG[32];
    __shared__ u32 doneCnt;   // # finalized groups; NGRP+9 = early-exit sentinel
    __shared__ u32 wpref[96];
    for (int k = tid; k < 96; k += 512) keepAll[k] = 0ull;
    if (tid == 0) doneCnt = 0u;
    __syncthreads();
    u64 lmask = (1ull << lane) - 1ull;   // bits strictly below my lane

    for (int s = 0; s < 3; ++s) {
        int G = s * 8 + g;
        if (G >= NGRP) break;
        int w0 = 4 * G;
        int nwg = NW - w0; if (nwg > 4) nwg = 4;       // 4, or 3 for the last group
        int q0 = 64 * w0 + lane;
        int q1 = q0 + 64;
        int q2 = q0 + 128;
        int q3 = (nwg > 3) ? (q0 + 192) : q0;          // clamp: avoid OOB reads
        // 4x4 tile (i<=j): t{j}{i} = column w0+i of word-(w0+j) rows
        u64 t00 = FC(w0, q0);
        u64 t10 = (nwg > 1) ? FC(w0, q1) : 0ull;
        u64 t11 = (nwg > 1) ? FC(w0 + 1, q1) : 0ull;
        u64 t20 = (nwg > 2) ? FC(w0, q2) : 0ull;
        u64 t21 = (nwg > 2) ? FC(w0 + 1, q2) : 0ull;
        u64 t22 = (nwg > 2) ? FC(w0 + 2, q2) : 0ull;
        u64 t30 = (nwg > 3) ? FC(w0, q3) : 0ull;
        u64 t31 = (nwg > 3) ? FC(w0 + 1, q3) : 0ull;
        u64 t32 = (nwg > 3) ? FC(w0 + 2, q3) : 0ull;
        u64 t33 = (nwg > 3) ? FC(w0 + 3, q3) : 0ull;
        u64 v0 = validm[w0];
        u64 v1 = (nwg > 1) ? validm[w0 + 1] : 0ull;
        u64 v2 = (nwg > 2) ? validm[w0 + 2] : 0ull;
        u64 v3 = (nwg > 3) ? validm[w0 + 3] : 0ull;
        u64 sup0 = 0, sup1 = 0, sup2 = 0, sup3 = 0;
        bool dead = false;

        // fold over predecessor words [0, w0): 2-word x 4-row double-buffered
        int d0 = 0;
        u64 c00=0,c01=0,c02=0,c03=0,c10=0,c11=0,c12=0,c13=0;
        if (w0 > 0) {
            c00 = FC(0, q0); c01 = FC(0, q1); c02 = FC(0, q2); c03 = FC(0, q3);
            c10 = FC(1, q0); c11 = FC(1, q1); c12 = FC(1, q2); c13 = FC(1, q3);
        }
        asm volatile("" ::: "memory");   // pin load issue before the spin
        while (d0 < w0) {
            int d1 = d0 + 2;
            u64 n00=0,n01=0,n02=0,n03=0,n10=0,n11=0,n12=0,n13=0;
            if (d1 < w0) {
                n00 = FC(d1, q0);     n01 = FC(d1, q1);     n02 = FC(d1, q2);     n03 = FC(d1, q3);
                n10 = FC(d1 + 1, q0); n11 = FC(d1 + 1, q1); n12 = FC(d1 + 1, q2); n13 = FC(d1 + 1, q3);
            }
            asm volatile("" ::: "memory");   // pin prefetch issue before the spin
            WAITG(((d0 + 1) >> 2) + 1)       // groups covering words d0,d0+1 final
            if (dead) break;
            u64 ka = keepAll[d0], kb = keepAll[d0 + 1];
            sup0 |= (ka & c00) | (kb & c10);
            sup1 |= (ka & c01) | (kb & c11);
            sup2 |= (ka & c02) | (kb & c12);
            sup3 |= (ka & c03) | (kb & c13);
            c00=n00;c01=n01;c02=n02;c03=n03;c10=n10;c11=n11;c12=n12;c13=n13;
            d0 = d1;
        }
        // final fold batch waited doneCnt >= G: all predecessors final & folded
        if (!dead) {
            u32 tp = (G > 0) ? totG[G - 1] : 0u;
            u64 k0 = 0, k1 = 0, k2 = 0, k3 = 0;
            if (tp < POST_K) {
                k0 = nms_solve(v0, sup0, t00 & lmask);
                sup1 |= k0 & t10; sup2 |= k0 & t20; sup3 |= k0 & t30;
                k1 = nms_solve(v1, sup1, t11 & lmask);
                sup2 |= k1 & t21; sup3 |= k1 & t31;
                k2 = nms_solve(v2, sup2, t22 & lmask);
                sup3 |= k2 & t32;
                k3 = nms_solve(v3, sup3, t33 & lmask);
            }
            if (lane == 0) {
                keepAll[w0]     = k0;          // w0+3 <= 79 < 96: in-bounds
                keepAll[w0 + 1] = k1;
                keepAll[w0 + 2] = k2;
                keepAll[w0 + 3] = k3;
                u32 tk = tp + (u32)(__popcll(k0) + __popcll(k1) + __popcll(k2) + __popcll(k3));
                totG[G] = tk;
                asm volatile("s_waitcnt lgkmcnt(0)" ::: "memory");   // order LDS before flag
                __hip_atomic_store(&doneCnt,
                                   (tk >= POST_K) ? (u32)(NGRP + 9) : (u32)(G + 1),
                                   __ATOMIC_RELAXED, __HIP_MEMORY_SCOPE_WORKGROUP);
            }
        } else {
            break;   // sentinel observed: all later groups dead too (keepAll stays 0)
        }
    }
    __syncthreads();

    // word-prefix ranks
    if (tid == 0) {
        u32 s = 0;
        for (int w = 0; w < NW; ++w) { wpref[w] = s; s += (u32)__popcll(keepAll[w]); }
        wpref[NW] = s;
    }
    __syncthreads();
    u32 totk = wpref[NW]; if (totk > POST_K) totk = POST_K;
    for (int r = tid; r < PRE_K; r += 512) {
        int w = r >> 6, b = r & 63;
        u64 kw = keepAll[w];
        if ((kw >> b) & 1ull) {
            u32 rank = wpref[w] + (u32)__popcll(kw & ((1ull << b) - 1ull));
            if (rank < POST_K) {
                const float* src = rows + (size_t)r * 16;
                float* dst = out + (size_t)rank * 15;
#pragma unroll
                for (int c2 = 0; c2 < 15; ++c2) dst[c2] = src[c2];
            }
        }
    }
    for (int r = (int)totk + tid; r < POST_K; r += 512) {
        float* dst = out + (size_t)r * 15;
#pragma unroll
        for (int c2 = 0; c2 < 15; ++c2) dst[c2] = 0.f;
    }
}

extern "C" void kernel_launch(void* const* d_in, const int* in_sizes, int n_in,
                              void* d_out, int out_size, void* d_ws, size_t ws_size,
                              hipStream_t stream) {
    const float* loc = (const float*)d_in[0];
    const float2* conf2 = (const float2*)d_in[1];
    const float* lmk = (const float*)d_in[2];
    const float* pri = (const float*)d_in[3];
    const int* imw = (const int*)d_in[4];
    const int* imh = (const int*)d_in[5];
    float* out = (float*)d_out;
    char* base = (char*)d_ws;

    // workspace layout (bytes); total 2,184,768 (< 3,808,896 proven in R3-R19)
    u32* hist   = (u32*)(base + 0);         //  32768  [zeroed by memset]
    u32* bfill  = (u32*)(base + 32768);     //  32768  [zeroed]
    u32* bsel   = (u32*)(base + 65536);     //  64     [zeroed]
    u64* validm = (u64*)(base + 65600);     //  1024   [zeroed]  -> zero [0,66624)
    u32* bstart = (u32*)(base + 67648);     //  32768
    u64* cand   = (u64*)(base + 100416);    //  65536
    float* rows = (float*)(base + 165952);  //  320000 (5000 x 16)
    float4* boxes = (float4*)(base + 485952); // 80896 (NPAD x 16)
    u64* cmask  = (u64*)(base + 566848);    //  1617920 (202240 u64, triangle-packed)

    hipMemsetAsync(d_ws, 0, 66624, stream);

    hist_kernel<<<(N_IN + 255) / 256, 256, 0, stream>>>(conf2, hist);
    scan_kernel<<<1, 1024, 0, stream>>>(hist, bsel, bstart);
    compact_kernel<<<(N_IN + 255) / 256, 256, 0, stream>>>(conf2, bsel, bstart, bfill, cand);
    rankdec_kernel<<<24, 256, 0, stream>>>(cand, bstart, bfill, bsel, (const float4*)loc,
                                           (const float4*)pri, lmk, imw, imh,
                                           (float4*)rows, boxes, validm);
    mask_kernel<<<NW * (NW + 1) / 2, 64, 0, stream>>>(boxes, cmask);
    reduce_scatter_kernel<<<1, 512, 0, stream>>>(cmask, validm, rows, out);
}